// Round 1
// baseline (61.648 us; speedup 1.0000x reference)
//
#include <hip/hip_runtime.h>

struct cplx { float x, y; };

__device__ __forceinline__ cplx cmul(cplx a, cplx b) {
    cplx r;
    r.x = fmaf(a.x, b.x, -(a.y * b.y));
    r.y = fmaf(a.x, b.y,  a.y * b.x);
    return r;
}

// u0*a0 + u1*a1 (complex), pure 4-deep FMA chains (8 instr, negates are free src mods)
__device__ __forceinline__ cplx cmadd2(cplx u0, cplx a0, cplx u1, cplx a1) {
    cplx r;
    r.x = fmaf(u0.x, a0.x, fmaf(-u0.y, a0.y, fmaf(u1.x, a1.x, -(u1.y * a1.y))));
    r.y = fmaf(u0.x, a0.y, fmaf( u0.y, a0.x, fmaf(u1.x, a1.y,   u1.y * a1.x)));
    return r;
}

__global__ __launch_bounds__(256) void quanv_kernel(const float* __restrict__ x,
                                                    const float* __restrict__ prm,
                                                    float* __restrict__ out,
                                                    int n) {
    // Per-block uniform gate precompute into LDS.
    //  gates 0-3 (layer 0): full U = RZ*RY*RX           -> gs[8w .. 8w+7]
    //  gates 4-6 (layer 1, wires 0-2): U = RY*RX only   -> gs[8(4+w)..]
    //     (layer-1 RZ is diagonal; followed only by a basis permutation + |.|^2,
    //      so it cannot affect the output -- dropped exactly.)
    //  gate 7 (layer 1, wire 3): folded into measurement as W = U7^dag Z U7
    //     W = [[w0, wc],[wc*, -w0]],  w0 = cos a cos b, wc = (-sin b, -sin a cos b)
    //     stored as gs[56]=w0, gs[57]=2*Re(wc), gs[58]=2*Im(wc)
    __shared__ float gs[64];
    int tid = threadIdx.x;
    if (tid < 7) {
        float sa, ca, sb, cb;
        __sincosf(0.5f * prm[tid * 3 + 0], &sa, &ca);
        __sincosf(0.5f * prm[tid * 3 + 1], &sb, &cb);
        cplx u00 = {  cb * ca,  sb * sa };   // RY*RX
        cplx u01 = { -sb * ca, -cb * sa };
        cplx u10 = {  sb * ca, -cb * sa };
        cplx u11 = {  cb * ca, -sb * sa };
        if (tid < 4) {                       // layer 0 keeps its RZ
            float sc, cc;
            __sincosf(0.5f * prm[tid * 3 + 2], &sc, &cc);
            cplx em = { cc, -sc }, ep = { cc, sc };
            u00 = cmul(em, u00); u01 = cmul(em, u01);
            u10 = cmul(ep, u10); u11 = cmul(ep, u11);
        }
        float* o = gs + tid * 8;
        o[0] = u00.x; o[1] = u00.y; o[2] = u01.x; o[3] = u01.y;
        o[4] = u10.x; o[5] = u10.y; o[6] = u11.x; o[7] = u11.y;
    } else if (tid == 7) {
        float sa, ca, sb, cb;                // FULL angles here
        __sincosf(prm[21], &sa, &ca);        // a = RX angle, wire 3 layer 1
        __sincosf(prm[22], &sb, &cb);        // b = RY angle
        gs[56] = ca * cb;                    // w0
        gs[57] = -2.0f * sb;                 // 2*Re(wc)
        gs[58] = -2.0f * sa * cb;            // 2*Im(wc)
    }
    __syncthreads();

    int t = blockIdx.x * 256 + tid;
    if (t >= n) return;

    int b  = t / 196;
    int pi = t - b * 196;
    int r  = pi / 14;
    int c  = pi - r * 14;

    const float* xb = x + b * 784 + r * 56 + c * 2;
    float2 top = *(const float2*)(xb);
    float2 bot = *(const float2*)(xb + 28);
    float ang[4] = { top.x, top.y, bot.x, bot.y };

    // Encoding RY fused with layer-0 single-qubit gate: v_w = U_w * (c,s)^T
    cplx v[4][2];
#pragma unroll
    for (int w = 0; w < 4; ++w) {
        float cw, sw;
        __sincosf(0.5f * ang[w], &sw, &cw);
        const float* o = gs + w * 8;            // LDS broadcast reads
        v[w][0].x = fmaf(cw, o[0], sw * o[2]);
        v[w][0].y = fmaf(cw, o[1], sw * o[3]);
        v[w][1].x = fmaf(cw, o[4], sw * o[6]);
        v[w][1].y = fmaf(cw, o[5], sw * o[7]);
    }

    // Product state with layer-0 CNOT ring fused as a compile-time permutation.
    cplx p01[4], p23[4], st[16];
#pragma unroll
    for (int j = 0; j < 4; ++j) {
        p01[j] = cmul(v[0][j >> 1], v[1][j & 1]);
        p23[j] = cmul(v[2][j >> 1], v[3][j & 1]);
    }
#pragma unroll
    for (int j = 0; j < 16; ++j) {
        int w0b = (j >> 3) & 1, w1 = (j >> 2) & 1, w2 = (j >> 1) & 1, w3 = j & 1;
        int n1 = w1 ^ w0b;
        int n2 = w2 ^ w1 ^ w0b;
        int n3 = w3 ^ w2 ^ w1 ^ w0b;
        int n0 = w3 ^ w2 ^ w1;
        int pj = (n0 << 3) | (n1 << 2) | (n2 << 1) | n3;   // compile-time
        st[pj] = cmul(p01[j >> 2], p23[j & 3]);
    }

    // Layer-1 single-qubit gates on wires 0..2 only (gate 3 is folded below)
#pragma unroll
    for (int w = 0; w < 3; ++w) {
        const float* o = gs + (4 + w) * 8;
        cplx u00 = { o[0], o[1] }, u01 = { o[2], o[3] };
        cplx u10 = { o[4], o[5] }, u11 = { o[6], o[7] };
        int strd = 8 >> w;
#pragma unroll
        for (int i = 0; i < 16; ++i) {
            if (i & strd) continue;
            cplx a0 = st[i], a1 = st[i + strd];
            st[i]        = cmadd2(u00, a0, u01, a1);
            st[i + strd] = cmadd2(u10, a0, u11, a1);
        }
    }

    // Wire-3 gate folded into the measurement (strd == 1 pairs):
    //   as[k] = |b0|^2+|b1|^2 = |a0|^2+|a1|^2           (unitarity)
    //   ad[k] = |b0|^2-|b1|^2 = <a| W |a>
    //         = w0*(n0-n1) + (2wcr)*Re(conj(a0)a1) - (2wci)*Im(conj(a0)a1)
    const float w0f = gs[56], wr2 = gs[57], wi2 = gs[58];
    float as[8], ad[8];
#pragma unroll
    for (int k = 0; k < 8; ++k) {
        cplx a0 = st[2 * k], a1 = st[2 * k + 1];
        float n0 = fmaf(a0.x, a0.x, a0.y * a0.y);
        float n1 = fmaf(a1.x, a1.x, a1.y * a1.y);
        float zr = fmaf(a0.x, a1.x, a0.y * a1.y);     // Re(conj(a0)*a1)
        float zi = fmaf(a0.x, a1.y, -(a0.y * a1.x));  // Im(conj(a0)*a1)
        as[k] = n0 + n1;
        ad[k] = fmaf(w0f, n0 - n1, fmaf(wr2, zr, -(wi2 * zi)));
    }

    // Final CNOT ring folded into observables (Clifford pushthrough):
    // state-bit parity masks: ev0:7, ev1:12, ev2:14, ev3:15.
    float bss[4], bsd[4], bdd[4];
#pragma unroll
    for (int i = 0; i < 4; ++i) {
        bss[i] = as[2 * i] + as[2 * i + 1];
        bsd[i] = as[2 * i] - as[2 * i + 1];
        bdd[i] = ad[2 * i] - ad[2 * i + 1];
    }
    float ev1 = (bss[0] - bss[1]) - (bss[2] - bss[3]);   // mask 12
    float ev2 = (bsd[0] - bsd[1]) - (bsd[2] - bsd[3]);   // mask 14
    float ev0 = (bdd[0] - bdd[1]) + (bdd[2] - bdd[3]);   // mask 7
    float ev3 = (bdd[0] - bdd[1]) - (bdd[2] - bdd[3]);   // mask 15

    float4 o4 = { ev0, ev1, ev2, ev3 };
    *(float4*)(out + t * 4) = o4;
}

extern "C" void kernel_launch(void* const* d_in, const int* in_sizes, int n_in,
                              void* d_out, int out_size, void* d_ws, size_t ws_size,
                              hipStream_t stream) {
    const float* x   = (const float*)d_in[0];
    const float* prm = (const float*)d_in[1];
    float* out = (float*)d_out;

    int B = in_sizes[0] / 784;   // (B,1,28,28)
    int n = B * 196;             // patches total
    int block = 256;
    int grid = (n + block - 1) / block;
    quanv_kernel<<<grid, block, 0, stream>>>(x, prm, out, n);
}